// Round 1
// baseline (810.721 us; speedup 1.0000x reference)
//
#include <hip/hip_runtime.h>
#include <math.h>

#define BB   8
#define NN   1024
#define SS   128
#define KK   32
#define EMB  384

// ---------------------------------------------------------------------------
// Kernel 1: farthest point sampling, one block per cloud.
// Matches jnp semantics: idx[0]=0; idx[s]=argmax(mind) after update with
// p[idx[s-1]]; ties -> lowest index. No FMA contraction in distance calc.
// ---------------------------------------------------------------------------
__global__ __launch_bounds__(256) void fps_kernel(
    const float* __restrict__ pos,
    int* __restrict__ seed_idx,
    float* __restrict__ seed_pos)
{
    const int b = blockIdx.x;
    const int t = threadIdx.x;
    const float* p = pos + (size_t)b * NN * 3;

    float px[4], py[4], pz[4], mind[4];
#pragma unroll
    for (int r = 0; r < 4; ++r) {
        const int i = t + r * 256;
        px[r] = p[i * 3 + 0];
        py[r] = p[i * 3 + 1];
        pz[r] = p[i * 3 + 2];
        mind[r] = INFINITY;
    }

    __shared__ float s_val[256];
    __shared__ int   s_idx[256];

    int last = 0;
    for (int s = 0; s < SS; ++s) {
        const float sx = p[last * 3 + 0];
        const float sy = p[last * 3 + 1];
        const float sz = p[last * 3 + 2];
        if (t == 0) {
            seed_idx[b * SS + s] = last;
            seed_pos[(b * SS + s) * 3 + 0] = sx;
            seed_pos[(b * SS + s) * 3 + 1] = sy;
            seed_pos[(b * SS + s) * 3 + 2] = sz;
        }
        float best = -INFINITY;
        int bi = 0;
#pragma unroll
        for (int r = 0; r < 4; ++r) {
            const float dx = __fsub_rn(px[r], sx);
            const float dy = __fsub_rn(py[r], sy);
            const float dz = __fsub_rn(pz[r], sz);
            const float d = __fadd_rn(__fadd_rn(__fmul_rn(dx, dx), __fmul_rn(dy, dy)),
                                      __fmul_rn(dz, dz));
            mind[r] = fminf(mind[r], d);
            if (mind[r] > best) { best = mind[r]; bi = t + r * 256; }  // ascending idx, strict >
        }
        s_val[t] = best;
        s_idx[t] = bi;
        __syncthreads();
        for (int off = 128; off > 0; off >>= 1) {
            if (t < off) {
                const float v2 = s_val[t + off];
                const int   i2 = s_idx[t + off];
                if (v2 > s_val[t] || (v2 == s_val[t] && i2 < s_idx[t])) {
                    s_val[t] = v2; s_idx[t] = i2;
                }
            }
            __syncthreads();
        }
        last = s_idx[0];
        __syncthreads();
    }
}

// ---------------------------------------------------------------------------
// Kernel 2: kNN, one block per seed. Iterative argmin (K=32 rounds) with
// lowest-index tie-break == stable top_k set selection.
// ---------------------------------------------------------------------------
__global__ __launch_bounds__(256) void knn_kernel(
    const float* __restrict__ pos,
    const float* __restrict__ seed_pos,
    int* __restrict__ nbr)
{
    const int blk = blockIdx.x;          // b*SS + s
    const int b = blk >> 7;
    const int t = threadIdx.x;
    const float* p = pos + (size_t)b * NN * 3;

    __shared__ float s_d[NN];
    __shared__ float s_val[256];
    __shared__ int   s_idx[256];

    const float sx = seed_pos[blk * 3 + 0];
    const float sy = seed_pos[blk * 3 + 1];
    const float sz = seed_pos[blk * 3 + 2];
#pragma unroll
    for (int r = 0; r < 4; ++r) {
        const int i = t + r * 256;
        const float dx = __fsub_rn(p[i * 3 + 0], sx);
        const float dy = __fsub_rn(p[i * 3 + 1], sy);
        const float dz = __fsub_rn(p[i * 3 + 2], sz);
        s_d[i] = __fadd_rn(__fadd_rn(__fmul_rn(dx, dx), __fmul_rn(dy, dy)),
                           __fmul_rn(dz, dz));
    }
    __syncthreads();

    for (int it = 0; it < KK; ++it) {
        float best = INFINITY;
        int bi = NN;
#pragma unroll
        for (int r = 0; r < 4; ++r) {
            const int i = t + r * 256;
            const float d = s_d[i];
            if (d < best) { best = d; bi = i; }   // ascending idx, strict <
        }
        s_val[t] = best;
        s_idx[t] = bi;
        __syncthreads();
        for (int off = 128; off > 0; off >>= 1) {
            if (t < off) {
                const float v2 = s_val[t + off];
                const int   i2 = s_idx[t + off];
                if (v2 < s_val[t] || (v2 == s_val[t] && i2 < s_idx[t])) {
                    s_val[t] = v2; s_idx[t] = i2;
                }
            }
            __syncthreads();
        }
        if (t == 0) {
            const int w = s_idx[0];
            nbr[blk * KK + it] = w;
            s_d[w] = INFINITY;
        }
        __syncthreads();
    }
}

// ---------------------------------------------------------------------------
// Kernel 3: PointConv, one block (256 threads) per seed.
//   rel[32][3] -> h1[32][128] (ReLU) -> f[32][256] -> g[256]=max_k f
//   h[k] = [g, f[k]] (512) -> h2[32][512] (ReLU) -> e[32][384] -> max_k -> out
// Weights are streamed from global exactly once per block into registers;
// activations live in LDS and are read as broadcasts / float4.
// LDS: h2[32][512] (h1 aliases its head) + f[32][256] + g[256] + rel ~ 97.5 KB
// ---------------------------------------------------------------------------
__global__ __launch_bounds__(256) void conv_kernel(
    const float* __restrict__ pos,
    const float* __restrict__ seed_pos,
    const int* __restrict__ nbr,
    const float* __restrict__ W1a, const float* __restrict__ b1a,
    const float* __restrict__ W1b, const float* __restrict__ b1b,
    const float* __restrict__ W2a, const float* __restrict__ b2a,
    const float* __restrict__ W2b, const float* __restrict__ b2b,
    float* __restrict__ out)
{
    __shared__ __align__(16) float smem[16384 + 8192 + 256 + 128];
    float* s_h2  = smem;                  // [32][512]
    float* s_h1  = smem;                  // [32][128], aliases head of h2 (dead before h2 written)
    float* s_f   = smem + 16384;          // [32][256]
    float* s_g   = smem + 16384 + 8192;   // [256] (reused as reduction buffer later)
    float* s_rel = smem + 16384 + 8192 + 256;  // [32][3]

    const int blk = blockIdx.x;           // seed id, 0..1023
    const int b = blk >> 7;
    const int t = threadIdx.x;

    // --- gather rel = nbr_pos - seed ---
    if (t < KK) {
        const int pi = nbr[blk * KK + t];
        const float* pp = pos + ((size_t)b * NN + pi) * 3;
        s_rel[t * 3 + 0] = pp[0] - seed_pos[blk * 3 + 0];
        s_rel[t * 3 + 1] = pp[1] - seed_pos[blk * 3 + 1];
        s_rel[t * 3 + 2] = pp[2] - seed_pos[blk * 3 + 2];
    }
    __syncthreads();

    // --- h1[32][128] = relu(rel @ W1a + b1a) ---
    {
        const int j = t & 127;
        const int k0 = t >> 7;
        const float w0 = W1a[j], w1 = W1a[128 + j], w2 = W1a[256 + j];
        const float bb = b1a[j];
        for (int k = k0; k < KK; k += 2) {
            float v = fmaf(s_rel[k * 3 + 2], w2,
                      fmaf(s_rel[k * 3 + 1], w1,
                      fmaf(s_rel[k * 3 + 0], w0, bb)));
            s_h1[k * 128 + j] = fmaxf(v, 0.0f);
        }
    }
    __syncthreads();

    // --- f[32][256] = h1 @ W1b + b1b ; g = max_k f ---
    {
        float acc[KK];
        const float bb = b1b[t];
#pragma unroll
        for (int k = 0; k < KK; ++k) acc[k] = bb;
        for (int j = 0; j < 128; j += 4) {
            const float w0 = W1b[(j + 0) * 256 + t];
            const float w1 = W1b[(j + 1) * 256 + t];
            const float w2 = W1b[(j + 2) * 256 + t];
            const float w3 = W1b[(j + 3) * 256 + t];
#pragma unroll
            for (int k = 0; k < KK; ++k) {
                const float4 h4 = *(const float4*)(s_h1 + k * 128 + j);
                acc[k] = fmaf(h4.x, w0, acc[k]);
                acc[k] = fmaf(h4.y, w1, acc[k]);
                acc[k] = fmaf(h4.z, w2, acc[k]);
                acc[k] = fmaf(h4.w, w3, acc[k]);
            }
        }
        float gmax = -INFINITY;
#pragma unroll
        for (int k = 0; k < KK; ++k) {
            s_f[k * 256 + t] = acc[k];
            gmax = fmaxf(gmax, acc[k]);
        }
        s_g[t] = gmax;
    }
    __syncthreads();

    // --- base[c2] = b2a[c2] + sum_{j<256} g[j]*W2a[j][c2]  (k-independent part) ---
    float base0 = b2a[t];
    float base1 = b2a[256 + t];
    for (int j = 0; j < 256; j += 4) {
        const float4 g4 = *(const float4*)(s_g + j);
        base0 = fmaf(g4.x, W2a[(j + 0) * 512 + t],       base0);
        base1 = fmaf(g4.x, W2a[(j + 0) * 512 + 256 + t], base1);
        base0 = fmaf(g4.y, W2a[(j + 1) * 512 + t],       base0);
        base1 = fmaf(g4.y, W2a[(j + 1) * 512 + 256 + t], base1);
        base0 = fmaf(g4.z, W2a[(j + 2) * 512 + t],       base0);
        base1 = fmaf(g4.z, W2a[(j + 2) * 512 + 256 + t], base1);
        base0 = fmaf(g4.w, W2a[(j + 3) * 512 + t],       base0);
        base1 = fmaf(g4.w, W2a[(j + 3) * 512 + 256 + t], base1);
    }

    // --- h2[32][512] = relu(base + sum_{j<256} f[k][j]*W2a[256+j][c2]) ---
    {
        float a0[KK], a1[KK];
#pragma unroll
        for (int k = 0; k < KK; ++k) { a0[k] = base0; a1[k] = base1; }
        for (int j = 0; j < 256; j += 4) {
            const float w00 = W2a[(256 + j + 0) * 512 + t];
            const float w01 = W2a[(256 + j + 0) * 512 + 256 + t];
            const float w10 = W2a[(256 + j + 1) * 512 + t];
            const float w11 = W2a[(256 + j + 1) * 512 + 256 + t];
            const float w20 = W2a[(256 + j + 2) * 512 + t];
            const float w21 = W2a[(256 + j + 2) * 512 + 256 + t];
            const float w30 = W2a[(256 + j + 3) * 512 + t];
            const float w31 = W2a[(256 + j + 3) * 512 + 256 + t];
#pragma unroll
            for (int k = 0; k < KK; ++k) {
                const float4 f4 = *(const float4*)(s_f + k * 256 + j);
                a0[k] = fmaf(f4.x, w00, a0[k]);  a1[k] = fmaf(f4.x, w01, a1[k]);
                a0[k] = fmaf(f4.y, w10, a0[k]);  a1[k] = fmaf(f4.y, w11, a1[k]);
                a0[k] = fmaf(f4.z, w20, a0[k]);  a1[k] = fmaf(f4.z, w21, a1[k]);
                a0[k] = fmaf(f4.w, w30, a0[k]);  a1[k] = fmaf(f4.w, w31, a1[k]);
            }
        }
        __syncthreads();   // h1 (aliased) fully dead; f reads done by all threads? f reads are
                           // in this stage only; h2 writes don't overlap s_f, but keep order clean.
#pragma unroll
        for (int k = 0; k < KK; ++k) {
            s_h2[k * 512 + t]       = fmaxf(a0[k], 0.0f);
            s_h2[k * 512 + 256 + t] = fmaxf(a1[k], 0.0f);
        }
    }
    __syncthreads();

    // --- e cols 0..255 (all threads): e[k][t] = b2b[t] + h2[k] . W2b[:,t]; out = max_k ---
    {
        float e0[KK];
        const float bb = b2b[t];
#pragma unroll
        for (int k = 0; k < KK; ++k) e0[k] = bb;
        for (int j = 0; j < 512; j += 4) {
            const float w0 = W2b[(j + 0) * EMB + t];
            const float w1 = W2b[(j + 1) * EMB + t];
            const float w2 = W2b[(j + 2) * EMB + t];
            const float w3 = W2b[(j + 3) * EMB + t];
#pragma unroll
            for (int k = 0; k < KK; ++k) {
                const float4 h4 = *(const float4*)(s_h2 + k * 512 + j);
                e0[k] = fmaf(h4.x, w0, e0[k]);
                e0[k] = fmaf(h4.y, w1, e0[k]);
                e0[k] = fmaf(h4.z, w2, e0[k]);
                e0[k] = fmaf(h4.w, w3, e0[k]);
            }
        }
        float m = e0[0];
#pragma unroll
        for (int k = 1; k < KK; ++k) m = fmaxf(m, e0[k]);
        out[(size_t)blk * EMB + t] = m;
    }

    // --- e cols 256..383: 128 cols, k split over two halves of the block ---
    {
        const int col = 256 + (t & 127);
        const int kh = t >> 7;   // 0 or 1 -> k in [kh*16, kh*16+16)
        float e1[16];
        const float bb = b2b[col];
#pragma unroll
        for (int kk = 0; kk < 16; ++kk) e1[kk] = bb;
        for (int j = 0; j < 512; j += 4) {
            const float w0 = W2b[(j + 0) * EMB + col];
            const float w1 = W2b[(j + 1) * EMB + col];
            const float w2 = W2b[(j + 2) * EMB + col];
            const float w3 = W2b[(j + 3) * EMB + col];
#pragma unroll
            for (int kk = 0; kk < 16; ++kk) {
                const int k = kh * 16 + kk;
                const float4 h4 = *(const float4*)(s_h2 + k * 512 + j);
                e1[kk] = fmaf(h4.x, w0, e1[kk]);
                e1[kk] = fmaf(h4.y, w1, e1[kk]);
                e1[kk] = fmaf(h4.z, w2, e1[kk]);
                e1[kk] = fmaf(h4.w, w3, e1[kk]);
            }
        }
        float m = e1[0];
#pragma unroll
        for (int kk = 1; kk < 16; ++kk) m = fmaxf(m, e1[kk]);
        s_g[t] = m;               // s_g reused as [2][128] reduction buffer
        __syncthreads();
        if (t < 128) {
            out[(size_t)blk * EMB + col] = fmaxf(s_g[t], s_g[t + 128]);
        }
    }
}

// ---------------------------------------------------------------------------
extern "C" void kernel_launch(void* const* d_in, const int* in_sizes, int n_in,
                              void* d_out, int out_size, void* d_ws, size_t ws_size,
                              hipStream_t stream)
{
    const float* pos = (const float*)d_in[0];
    // d_in[1] = batch (int32) — unused, clouds are contiguous
    const float* W1a = (const float*)d_in[2];
    const float* b1a = (const float*)d_in[3];
    const float* W1b = (const float*)d_in[4];
    const float* b1b = (const float*)d_in[5];
    const float* W2a = (const float*)d_in[6];
    const float* b2a = (const float*)d_in[7];
    const float* W2b = (const float*)d_in[8];
    const float* b2b = (const float*)d_in[9];
    float* out = (float*)d_out;

    char* ws = (char*)d_ws;
    int*   seed_idx = (int*)ws;                        // 1024 ints
    float* seed_pos = (float*)(ws + 4096);             // 1024*3 floats
    int*   nbr      = (int*)(ws + 4096 + 12288);       // 1024*32 ints

    fps_kernel<<<BB, 256, 0, stream>>>(pos, seed_idx, seed_pos);
    knn_kernel<<<BB * SS, 256, 0, stream>>>(pos, seed_pos, nbr);
    conv_kernel<<<BB * SS, 256, 0, stream>>>(pos, seed_pos, nbr,
                                             W1a, b1a, W1b, b1b,
                                             W2a, b2a, W2b, b2b, out);
}

// Round 2
// 407.508 us; speedup vs baseline: 1.9895x; 1.9895x over previous
//
#include <hip/hip_runtime.h>
#include <math.h>

#define BB   8
#define NN   1024
#define SS   128
#define KK   32
#define EMB  384

typedef __attribute__((ext_vector_type(4))) float f32x4;
typedef __attribute__((ext_vector_type(8))) short s16x8;

__device__ __forceinline__ unsigned short f2bf(float x) {
    unsigned u = __float_as_uint(x);
    unsigned r = (u + 0x7FFFu + ((u >> 16) & 1u)) >> 16;   // RN-even
    return (unsigned short)r;
}
__device__ __forceinline__ float bf2f(unsigned short h) {
    return __uint_as_float(((unsigned)h) << 16);
}
__device__ __forceinline__ f32x4 mfma16(s16x8 a, s16x8 b, f32x4 c) {
    return __builtin_amdgcn_mfma_f32_16x16x32_bf16(a, b, c, 0, 0, 0);
}

// ---------------------------------------------------------------------------
// FPS: one wave per cloud, points register-resident (16/lane), shfl butterfly
// argmax with lowest-index tie-break. Distance arithmetic bitwise-identical
// to round 1 (matches np reference: ((dx*dx+dy*dy)+dz*dz), no FMA).
// ---------------------------------------------------------------------------
__global__ __launch_bounds__(64) void fps_kernel(
    const float* __restrict__ pos, float* __restrict__ seed_pos)
{
    const int b = blockIdx.x;
    const int l = threadIdx.x;
    const float* p = pos + (size_t)b * NN * 3;

    float px[16], py[16], pz[16], mind[16];
#pragma unroll
    for (int r = 0; r < 16; ++r) {
        const int i = r * 64 + l;
        px[r] = p[i * 3 + 0];
        py[r] = p[i * 3 + 1];
        pz[r] = p[i * 3 + 2];
        mind[r] = INFINITY;
    }

    float sx = __shfl(px[0], 0), sy = __shfl(py[0], 0), sz = __shfl(pz[0], 0);
    for (int s = 0; s < SS; ++s) {
        if (l == 0) {
            seed_pos[((size_t)b * SS + s) * 3 + 0] = sx;
            seed_pos[((size_t)b * SS + s) * 3 + 1] = sy;
            seed_pos[((size_t)b * SS + s) * 3 + 2] = sz;
        }
        if (s == SS - 1) break;
        float best = -INFINITY;
        int bi = 0;
#pragma unroll
        for (int r = 0; r < 16; ++r) {
            const float dx = __fsub_rn(px[r], sx);
            const float dy = __fsub_rn(py[r], sy);
            const float dz = __fsub_rn(pz[r], sz);
            const float d = __fadd_rn(__fadd_rn(__fmul_rn(dx, dx), __fmul_rn(dy, dy)),
                                      __fmul_rn(dz, dz));
            mind[r] = fminf(mind[r], d);
            if (mind[r] > best) { best = mind[r]; bi = r * 64 + l; }  // ascending idx
        }
#pragma unroll
        for (int off = 1; off < 64; off <<= 1) {
            const float ov = __shfl_xor(best, off);
            const int   oi = __shfl_xor(bi, off);
            if (ov > best || (ov == best && oi < bi)) { best = ov; bi = oi; }
        }
        const int wr = bi >> 6, wl = bi & 63;
        float cx = 0.f, cy = 0.f, cz = 0.f;
#pragma unroll
        for (int r = 0; r < 16; ++r) {            // no runtime indexing (scratch!)
            if (r == wr) { cx = px[r]; cy = py[r]; cz = pz[r]; }
        }
        sx = __shfl(cx, wl); sy = __shfl(cy, wl); sz = __shfl(cz, wl);
    }
}

// ---------------------------------------------------------------------------
// kNN: unchanged from round 1 (verified correct).
// ---------------------------------------------------------------------------
__global__ __launch_bounds__(256) void knn_kernel(
    const float* __restrict__ pos,
    const float* __restrict__ seed_pos,
    int* __restrict__ nbr)
{
    const int blk = blockIdx.x;
    const int b = blk >> 7;
    const int t = threadIdx.x;
    const float* p = pos + (size_t)b * NN * 3;

    __shared__ float s_d[NN];
    __shared__ float s_val[256];
    __shared__ int   s_idx[256];

    const float sx = seed_pos[blk * 3 + 0];
    const float sy = seed_pos[blk * 3 + 1];
    const float sz = seed_pos[blk * 3 + 2];
#pragma unroll
    for (int r = 0; r < 4; ++r) {
        const int i = t + r * 256;
        const float dx = __fsub_rn(p[i * 3 + 0], sx);
        const float dy = __fsub_rn(p[i * 3 + 1], sy);
        const float dz = __fsub_rn(p[i * 3 + 2], sz);
        s_d[i] = __fadd_rn(__fadd_rn(__fmul_rn(dx, dx), __fmul_rn(dy, dy)),
                           __fmul_rn(dz, dz));
    }
    __syncthreads();

    for (int it = 0; it < KK; ++it) {
        float best = INFINITY;
        int bi = NN;
#pragma unroll
        for (int r = 0; r < 4; ++r) {
            const int i = t + r * 256;
            const float d = s_d[i];
            if (d < best) { best = d; bi = i; }
        }
        s_val[t] = best;
        s_idx[t] = bi;
        __syncthreads();
        for (int off = 128; off > 0; off >>= 1) {
            if (t < off) {
                const float v2 = s_val[t + off];
                const int   i2 = s_idx[t + off];
                if (v2 < s_val[t] || (v2 == s_val[t] && i2 < s_idx[t])) {
                    s_val[t] = v2; s_idx[t] = i2;
                }
            }
            __syncthreads();
        }
        if (t == 0) {
            const int wdx = s_idx[0];
            nbr[blk * KK + it] = wdx;
            s_d[wdx] = INFINITY;
        }
        __syncthreads();
    }
}

// ---------------------------------------------------------------------------
// Prep: W [Ksrc][N] f32 (rows koff..koff+K-1) -> Wt_hi/lo [N][K] bf16 splits.
// ---------------------------------------------------------------------------
__global__ __launch_bounds__(256) void prep_split(
    const float* __restrict__ W, int N, int K, int koff,
    unsigned short* __restrict__ Th, unsigned short* __restrict__ Tl)
{
    const int idx = blockIdx.x * 256 + threadIdx.x;
    if (idx >= N * K) return;
    const int n = idx / K;
    const int k = idx - n * K;
    const float x = W[(size_t)(k + koff) * N + n];
    const unsigned short hi = f2bf(x);
    const unsigned short lo = f2bf(x - bf2f(hi));
    Th[idx] = hi;
    Tl[idx] = lo;
}

// ---------------------------------------------------------------------------
// PointConv via MFMA bf16x3, one block (4 waves) per seed.
//   stage1: h1[32][128] = relu(rel@W1a+b1a) f32 -> bf16 hi/lo LDS (swizzled)
//   GEMM1:  f = h1@W1b + b1b  (M=32,N=256,K=128); g = colmax(f)
//   base:   b2a + g@W2a[0:256]  (f32 VALU, rank-1 part of concat-K)
//   GEMM2:  h2 = relu(base + f@W2a[256:512])  (M=32,N=512,K=256)
//   GEMM3:  e  = h2@W2b; out = colmax(e) + b2b (M=32,N=384,K=512)
// A-operands in XOR-swizzled LDS ((row&7)<<4); B-fragments are direct 16-B
// global loads from the [N][K] pre-split weights (L2-resident).
// ---------------------------------------------------------------------------
__global__ __launch_bounds__(256, 1) void conv_kernel(
    const float* __restrict__ pos,
    const float* __restrict__ seed_pos,
    const int* __restrict__ nbr,
    const float* __restrict__ W1a, const float* __restrict__ b1a,
    const float* __restrict__ b1b,
    const float* __restrict__ W2a, const float* __restrict__ b2a,
    const float* __restrict__ b2b,
    const unsigned short* __restrict__ W1bt_h, const unsigned short* __restrict__ W1bt_l,
    const unsigned short* __restrict__ W2at_h, const unsigned short* __restrict__ W2at_l,
    const unsigned short* __restrict__ W2bt_h, const unsigned short* __restrict__ W2bt_l,
    float* __restrict__ out)
{
    __shared__ __align__(16) unsigned char smem[102784];
    unsigned char* sA3h = smem;                 // [32][1024B] swizzled h2_hi
    unsigned char* sA3l = smem + 32768;         // [32][1024B] swizzled h2_lo
    unsigned char* sH1h = smem;                 // [32][256B]  (aliases A3h head; dead before A3 write)
    unsigned char* sH1l = smem + 8192;          // [32][256B]
    unsigned char* sA2h = smem + 65536;         // [32][512B]  f_hi
    unsigned char* sA2l = smem + 81920;         // [32][512B]  f_lo
    float* s_g    = (float*)(smem + 98304);     // [256]
    float* s_base = (float*)(smem + 99328);     // [512]
    float* s_b1b  = (float*)(smem + 101376);    // [256]
    float* s_rel  = (float*)(smem + 102400);    // [32][3]

    const int blk = blockIdx.x;                 // seed 0..1023
    const int b   = blk >> 7;
    const int t   = threadIdx.x;
    const int w   = t >> 6;                     // wave 0..3
    const int l   = t & 63;
    const int lg  = l >> 4;
    const int l15 = l & 15;

    // ---- stage 0: gather rel, stage b1b ----
    s_b1b[t] = b1b[t];
    if (t < KK) {
        const int pi = nbr[blk * KK + t];
        const float* pp = pos + ((size_t)b * NN + pi) * 3;
        s_rel[t * 3 + 0] = pp[0] - seed_pos[blk * 3 + 0];
        s_rel[t * 3 + 1] = pp[1] - seed_pos[blk * 3 + 1];
        s_rel[t * 3 + 2] = pp[2] - seed_pos[blk * 3 + 2];
    }
    __syncthreads();

    // ---- stage 1: h1 ----
    {
        const int j  = t & 127;
        const int rg = t >> 7;
        const float w0 = W1a[j], w1 = W1a[128 + j], w2 = W1a[256 + j], bb = b1a[j];
#pragma unroll
        for (int rr = 0; rr < 16; ++rr) {
            const int row = rg * 16 + rr;
            float v = fmaf(s_rel[row * 3 + 2], w2,
                      fmaf(s_rel[row * 3 + 1], w1,
                      fmaf(s_rel[row * 3 + 0], w0, bb)));
            v = fmaxf(v, 0.0f);
            const unsigned short hi = f2bf(v);
            const unsigned short lo = f2bf(v - bf2f(hi));
            const int byte = (j * 2) ^ ((row & 7) << 4);
            *(unsigned short*)(sH1h + row * 256 + byte) = hi;
            *(unsigned short*)(sH1l + row * 256 + byte) = lo;
        }
    }
    __syncthreads();

    // ---- GEMM1: f = h1 @ W1b ----
    f32x4 C1[2][4];
#pragma unroll
    for (int m = 0; m < 2; ++m)
#pragma unroll
        for (int i = 0; i < 4; ++i) C1[m][i] = (f32x4){0.f, 0.f, 0.f, 0.f};
#pragma unroll
    for (int ks = 0; ks < 4; ++ks) {
        s16x8 ah[2], al[2], bh[4], bl[4];
#pragma unroll
        for (int m = 0; m < 2; ++m) {
            const int row = m * 16 + l15;
            const int byte = (lg * 16 + ks * 64) ^ ((row & 7) << 4);
            ah[m] = *(const s16x8*)(sH1h + row * 256 + byte);
            al[m] = *(const s16x8*)(sH1l + row * 256 + byte);
        }
#pragma unroll
        for (int i = 0; i < 4; ++i) {
            const int ncol = w * 64 + i * 16 + l15;
            const size_t off = (size_t)ncol * 128 + lg * 8 + ks * 32;
            bh[i] = *(const s16x8*)(W1bt_h + off);
            bl[i] = *(const s16x8*)(W1bt_l + off);
        }
#pragma unroll
        for (int i = 0; i < 4; ++i)
#pragma unroll
            for (int m = 0; m < 2; ++m) C1[m][i] = mfma16(ah[m], bh[i], C1[m][i]);
#pragma unroll
        for (int i = 0; i < 4; ++i)
#pragma unroll
            for (int m = 0; m < 2; ++m) C1[m][i] = mfma16(ah[m], bl[i], C1[m][i]);
#pragma unroll
        for (int i = 0; i < 4; ++i)
#pragma unroll
            for (int m = 0; m < 2; ++m) C1[m][i] = mfma16(al[m], bh[i], C1[m][i]);
    }
    // epi: f = C1 + b1b -> A2 split; g = colmax
#pragma unroll
    for (int i = 0; i < 4; ++i) {
        const int col = w * 64 + i * 16 + l15;
        const float bias = s_b1b[col];
        float pm = -INFINITY;
#pragma unroll
        for (int m = 0; m < 2; ++m)
#pragma unroll
            for (int r = 0; r < 4; ++r) {
                const float v = C1[m][i][r] + bias;
                pm = fmaxf(pm, v);
                const int row = m * 16 + lg * 4 + r;
                const unsigned short hi = f2bf(v);
                const unsigned short lo = f2bf(v - bf2f(hi));
                const int byte = (col * 2) ^ ((row & 7) << 4);
                *(unsigned short*)(sA2h + row * 512 + byte) = hi;
                *(unsigned short*)(sA2l + row * 512 + byte) = lo;
            }
        pm = fmaxf(pm, __shfl_xor(pm, 16));
        pm = fmaxf(pm, __shfl_xor(pm, 32));
        if (lg == 0) s_g[col] = pm;
    }
    __syncthreads();

    // ---- base[c] = b2a[c] + sum_{j<256} g[j]*W2a[j][c] ----
    {
        float acc0 = b2a[t];
        float acc1 = b2a[256 + t];
#pragma unroll 4
        for (int j = 0; j < 256; j += 4) {
            const float g0 = s_g[j], g1 = s_g[j + 1], g2 = s_g[j + 2], g3 = s_g[j + 3];
            const float* wp = W2a + (size_t)j * 512 + t;
            acc0 = fmaf(g0, wp[0],    acc0);  acc1 = fmaf(g0, wp[256],  acc1);
            acc0 = fmaf(g1, wp[512],  acc0);  acc1 = fmaf(g1, wp[768],  acc1);
            acc0 = fmaf(g2, wp[1024], acc0);  acc1 = fmaf(g2, wp[1280], acc1);
            acc0 = fmaf(g3, wp[1536], acc0);  acc1 = fmaf(g3, wp[1792], acc1);
        }
        s_base[t] = acc0;
        s_base[256 + t] = acc1;
    }
    __syncthreads();

    // ---- GEMM2: h2 = relu(base + f @ W2a[256:]) ----
    {
        f32x4 C2[2][8];
#pragma unroll
        for (int m = 0; m < 2; ++m)
#pragma unroll
            for (int n = 0; n < 8; ++n) C2[m][n] = (f32x4){0.f, 0.f, 0.f, 0.f};
#pragma unroll 2
        for (int ks = 0; ks < 8; ++ks) {
            s16x8 ah[2], al[2], bh[8], bl[8];
#pragma unroll
            for (int m = 0; m < 2; ++m) {
                const int row = m * 16 + l15;
                const int byte = (lg * 16 + ks * 64) ^ ((row & 7) << 4);
                ah[m] = *(const s16x8*)(sA2h + row * 512 + byte);
                al[m] = *(const s16x8*)(sA2l + row * 512 + byte);
            }
#pragma unroll
            for (int n = 0; n < 8; ++n) {
                const int ncol = w * 128 + n * 16 + l15;
                const size_t off = (size_t)ncol * 256 + lg * 8 + ks * 32;
                bh[n] = *(const s16x8*)(W2at_h + off);
                bl[n] = *(const s16x8*)(W2at_l + off);
            }
#pragma unroll
            for (int n = 0; n < 8; ++n)
#pragma unroll
                for (int m = 0; m < 2; ++m) C2[m][n] = mfma16(ah[m], bh[n], C2[m][n]);
#pragma unroll
            for (int n = 0; n < 8; ++n)
#pragma unroll
                for (int m = 0; m < 2; ++m) C2[m][n] = mfma16(ah[m], bl[n], C2[m][n]);
#pragma unroll
            for (int n = 0; n < 8; ++n)
#pragma unroll
                for (int m = 0; m < 2; ++m) C2[m][n] = mfma16(al[m], bh[n], C2[m][n]);
        }
        __syncthreads();   // all waves done reading h1-region (GEMM1) & A2; A3 writes may begin
#pragma unroll
        for (int n = 0; n < 8; ++n) {
            const int col = w * 128 + n * 16 + l15;
            const float bs = s_base[col];
#pragma unroll
            for (int m = 0; m < 2; ++m)
#pragma unroll
                for (int r = 0; r < 4; ++r) {
                    const float v = fmaxf(C2[m][n][r] + bs, 0.0f);
                    const int row = m * 16 + lg * 4 + r;
                    const unsigned short hi = f2bf(v);
                    const unsigned short lo = f2bf(v - bf2f(hi));
                    const int byte = (col * 2) ^ ((row & 7) << 4);
                    *(unsigned short*)(sA3h + row * 1024 + byte) = hi;
                    *(unsigned short*)(sA3l + row * 1024 + byte) = lo;
                }
        }
    }
    __syncthreads();

    // ---- GEMM3: e = h2 @ W2b; out = colmax(e) + b2b ----
    {
        f32x4 C3[2][6];
#pragma unroll
        for (int m = 0; m < 2; ++m)
#pragma unroll
            for (int n = 0; n < 6; ++n) C3[m][n] = (f32x4){0.f, 0.f, 0.f, 0.f};
#pragma unroll 2
        for (int ks = 0; ks < 16; ++ks) {
            s16x8 ah[2], al[2], bh[6], bl[6];
#pragma unroll
            for (int m = 0; m < 2; ++m) {
                const int row = m * 16 + l15;
                const int byte = (lg * 16 + ks * 64) ^ ((row & 7) << 4);
                ah[m] = *(const s16x8*)(sA3h + row * 1024 + byte);
                al[m] = *(const s16x8*)(sA3l + row * 1024 + byte);
            }
#pragma unroll
            for (int n = 0; n < 6; ++n) {
                const int ncol = w * 96 + n * 16 + l15;
                const size_t off = (size_t)ncol * 512 + lg * 8 + ks * 32;
                bh[n] = *(const s16x8*)(W2bt_h + off);
                bl[n] = *(const s16x8*)(W2bt_l + off);
            }
#pragma unroll
            for (int n = 0; n < 6; ++n)
#pragma unroll
                for (int m = 0; m < 2; ++m) C3[m][n] = mfma16(ah[m], bh[n], C3[m][n]);
#pragma unroll
            for (int n = 0; n < 6; ++n)
#pragma unroll
                for (int m = 0; m < 2; ++m) C3[m][n] = mfma16(ah[m], bl[n], C3[m][n]);
#pragma unroll
            for (int n = 0; n < 6; ++n)
#pragma unroll
                for (int m = 0; m < 2; ++m) C3[m][n] = mfma16(al[m], bh[n], C3[m][n]);
        }
#pragma unroll
        for (int n = 0; n < 6; ++n) {
            const int col = w * 96 + n * 16 + l15;
            float pm = -INFINITY;
#pragma unroll
            for (int m = 0; m < 2; ++m)
#pragma unroll
                for (int r = 0; r < 4; ++r) pm = fmaxf(pm, C3[m][n][r]);
            pm = fmaxf(pm, __shfl_xor(pm, 16));
            pm = fmaxf(pm, __shfl_xor(pm, 32));
            if (lg == 0) out[(size_t)blk * EMB + col] = pm + b2b[col];
        }
    }
}

// ---------------------------------------------------------------------------
extern "C" void kernel_launch(void* const* d_in, const int* in_sizes, int n_in,
                              void* d_out, int out_size, void* d_ws, size_t ws_size,
                              hipStream_t stream)
{
    const float* pos = (const float*)d_in[0];
    // d_in[1] = batch (unused; clouds contiguous)
    const float* W1a = (const float*)d_in[2];
    const float* b1a = (const float*)d_in[3];
    const float* W1b = (const float*)d_in[4];
    const float* b1b = (const float*)d_in[5];
    const float* W2a = (const float*)d_in[6];
    const float* b2a = (const float*)d_in[7];
    const float* W2b = (const float*)d_in[8];
    const float* b2b = (const float*)d_in[9];
    float* out = (float*)d_out;

    // workspace layout (1,589,248 B total)
    unsigned char* ws = (unsigned char*)d_ws;
    float* seed_pos = (float*)(ws + 0);                         // 12 KB
    int*   nbr      = (int*)(ws + 16384);                       // 128 KB
    unsigned short* W1bt_h = (unsigned short*)(ws + 147456);    // 64 KB  [256][128]
    unsigned short* W1bt_l = (unsigned short*)(ws + 212992);    // 64 KB
    unsigned short* W2at_h = (unsigned short*)(ws + 278528);    // 256 KB [512][256]
    unsigned short* W2at_l = (unsigned short*)(ws + 540672);    // 256 KB
    unsigned short* W2bt_h = (unsigned short*)(ws + 802816);    // 384 KB [384][512]
    unsigned short* W2bt_l = (unsigned short*)(ws + 1196032);   // 384 KB

    prep_split<<<(256 * 128 + 255) / 256, 256, 0, stream>>>(W1b, 256, 128, 0,   W1bt_h, W1bt_l);
    prep_split<<<(512 * 256 + 255) / 256, 256, 0, stream>>>(W2a, 512, 256, 256, W2at_h, W2at_l);
    prep_split<<<(384 * 512 + 255) / 256, 256, 0, stream>>>(W2b, 384, 512, 0,   W2bt_h, W2bt_l);
    fps_kernel<<<BB, 64, 0, stream>>>(pos, seed_pos);
    knn_kernel<<<BB * SS, 256, 0, stream>>>(pos, seed_pos, nbr);
    conv_kernel<<<BB * SS, 256, 0, stream>>>(pos, seed_pos, nbr,
                                             W1a, b1a, b1b, W2a, b2a, b2b,
                                             W1bt_h, W1bt_l, W2at_h, W2at_l,
                                             W2bt_h, W2bt_l, out);
}

// Round 3
// 378.889 us; speedup vs baseline: 2.1397x; 1.0755x over previous
//
#include <hip/hip_runtime.h>
#include <math.h>

#define BB   8
#define NN   1024
#define SS   128
#define KK   32
#define EMB  384

typedef __attribute__((ext_vector_type(4))) float f32x4;
typedef __attribute__((ext_vector_type(8))) short s16x8;

__device__ __forceinline__ unsigned short f2bf(float x) {
    unsigned u = __float_as_uint(x);
    unsigned r = (u + 0x7FFFu + ((u >> 16) & 1u)) >> 16;   // RN-even
    return (unsigned short)r;
}
__device__ __forceinline__ float bf2f(unsigned short h) {
    return __uint_as_float(((unsigned)h) << 16);
}
__device__ __forceinline__ f32x4 mfma16(s16x8 a, s16x8 b, f32x4 c) {
    return __builtin_amdgcn_mfma_f32_16x16x32_bf16(a, b, c, 0, 0, 0);
}

// ---------------------------------------------------------------------------
// FPS: one wave per cloud (verified round 2).
// ---------------------------------------------------------------------------
__global__ __launch_bounds__(64) void fps_kernel(
    const float* __restrict__ pos, float* __restrict__ seed_pos)
{
    const int b = blockIdx.x;
    const int l = threadIdx.x;
    const float* p = pos + (size_t)b * NN * 3;

    float px[16], py[16], pz[16], mind[16];
#pragma unroll
    for (int r = 0; r < 16; ++r) {
        const int i = r * 64 + l;
        px[r] = p[i * 3 + 0];
        py[r] = p[i * 3 + 1];
        pz[r] = p[i * 3 + 2];
        mind[r] = INFINITY;
    }

    float sx = __shfl(px[0], 0), sy = __shfl(py[0], 0), sz = __shfl(pz[0], 0);
    for (int s = 0; s < SS; ++s) {
        if (l == 0) {
            seed_pos[((size_t)b * SS + s) * 3 + 0] = sx;
            seed_pos[((size_t)b * SS + s) * 3 + 1] = sy;
            seed_pos[((size_t)b * SS + s) * 3 + 2] = sz;
        }
        if (s == SS - 1) break;
        float best = -INFINITY;
        int bi = 0;
#pragma unroll
        for (int r = 0; r < 16; ++r) {
            const float dx = __fsub_rn(px[r], sx);
            const float dy = __fsub_rn(py[r], sy);
            const float dz = __fsub_rn(pz[r], sz);
            const float d = __fadd_rn(__fadd_rn(__fmul_rn(dx, dx), __fmul_rn(dy, dy)),
                                      __fmul_rn(dz, dz));
            mind[r] = fminf(mind[r], d);
            if (mind[r] > best) { best = mind[r]; bi = r * 64 + l; }
        }
#pragma unroll
        for (int off = 1; off < 64; off <<= 1) {
            const float ov = __shfl_xor(best, off);
            const int   oi = __shfl_xor(bi, off);
            if (ov > best || (ov == best && oi < bi)) { best = ov; bi = oi; }
        }
        const int wr = bi >> 6, wl = bi & 63;
        float cx = 0.f, cy = 0.f, cz = 0.f;
#pragma unroll
        for (int r = 0; r < 16; ++r) {
            if (r == wr) { cx = px[r]; cy = py[r]; cz = pz[r]; }
        }
        sx = __shfl(cx, wl); sy = __shfl(cy, wl); sz = __shfl(cz, wl);
    }
}

// ---------------------------------------------------------------------------
// kNN: wave-per-seed. 8 waves/block, cloud staged once in LDS (SoA),
// per-lane distances in registers, 32 rounds of butterfly argmin
// (lowest-index tie-break == stable top_k set). No barriers in the loop.
// ---------------------------------------------------------------------------
__global__ __launch_bounds__(512) void knn_kernel(
    const float* __restrict__ pos,
    const float* __restrict__ seed_pos,
    int* __restrict__ nbr)
{
    __shared__ float sx_[NN], sy_[NN], sz_[NN];
    const int blk = blockIdx.x;            // 0..127
    const int b   = blk >> 4;              // cloud
    const int t   = threadIdx.x;
    const int w   = t >> 6;                // wave 0..7
    const int l   = t & 63;
    const float* p = pos + (size_t)b * NN * 3;

    for (int i = t; i < NN; i += 512) {
        sx_[i] = p[i * 3 + 0];
        sy_[i] = p[i * 3 + 1];
        sz_[i] = p[i * 3 + 2];
    }
    __syncthreads();

    const int gsid = b * SS + (blk & 15) * 8 + w;   // global seed id
    const float cx = seed_pos[gsid * 3 + 0];
    const float cy = seed_pos[gsid * 3 + 1];
    const float cz = seed_pos[gsid * 3 + 2];

    float d[16];
#pragma unroll
    for (int r = 0; r < 16; ++r) {
        const int i = r * 64 + l;
        const float dx = __fsub_rn(sx_[i], cx);
        const float dy = __fsub_rn(sy_[i], cy);
        const float dz = __fsub_rn(sz_[i], cz);
        d[r] = __fadd_rn(__fadd_rn(__fmul_rn(dx, dx), __fmul_rn(dy, dy)),
                         __fmul_rn(dz, dz));
    }

    for (int it = 0; it < KK; ++it) {
        float best = INFINITY;
        int bi = NN;
#pragma unroll
        for (int r = 0; r < 16; ++r) {
            if (d[r] < best) { best = d[r]; bi = r * 64 + l; }   // ascending idx
        }
#pragma unroll
        for (int off = 1; off < 64; off <<= 1) {
            const float ov = __shfl_xor(best, off);
            const int   oi = __shfl_xor(bi, off);
            if (ov < best || (ov == best && oi < bi)) { best = ov; bi = oi; }
        }
        const int wr = bi >> 6, wl = bi & 63;
#pragma unroll
        for (int r = 0; r < 16; ++r) {
            if (r == wr && l == wl) d[r] = INFINITY;
        }
        if (l == 0) nbr[(size_t)gsid * KK + it] = bi;
    }
}

// ---------------------------------------------------------------------------
// Prep (merged): W [Ksrc][N] f32 -> Wt_hi/lo [N][K] bf16 splits, 3 matrices.
// ---------------------------------------------------------------------------
__global__ __launch_bounds__(256) void prep_all(
    const float* __restrict__ W1b, const float* __restrict__ W2a,
    const float* __restrict__ W2b,
    unsigned short* __restrict__ W1bt_h, unsigned short* __restrict__ W1bt_l,
    unsigned short* __restrict__ W2at_h, unsigned short* __restrict__ W2at_l,
    unsigned short* __restrict__ W2bt_h, unsigned short* __restrict__ W2bt_l)
{
    const int idx = blockIdx.x * 256 + threadIdx.x;
    float x;
    unsigned short *ph, *pl;
    int j;
    if (idx < 32768) {                       // W1b: N=256, K=128
        j = idx;
        const int n = j >> 7, k = j & 127;
        x = W1b[(size_t)k * 256 + n];
        ph = W1bt_h; pl = W1bt_l;
    } else if (idx < 163840) {               // W2a bottom: N=512, K=256, koff=256
        j = idx - 32768;
        const int n = j >> 8, k = j & 255;
        x = W2a[(size_t)(k + 256) * 512 + n];
        ph = W2at_h; pl = W2at_l;
    } else if (idx < 360448) {               // W2b: N=384, K=512
        j = idx - 163840;
        const int n = j >> 9, k = j & 511;
        x = W2b[(size_t)k * 384 + n];
        ph = W2bt_h; pl = W2bt_l;
    } else {
        return;
    }
    const unsigned short hi = f2bf(x);
    const unsigned short lo = f2bf(x - bf2f(hi));
    ph[j] = hi;
    pl[j] = lo;
}

// ---------------------------------------------------------------------------
// PointConv via MFMA bf16x3, one block (4 waves) per seed, 3 blocks/CU.
// LDS map (52,608 B):
//   [0,16384)      H1 hi/lo   (stage1 -> GEMM1)         } aliased by
//   [16384,49152)  A2 hi/lo   (GEMM1 epi -> GEMM2)      }  A3half
//   [0,32768)      A3half hi/lo (h2 staged in 2 K-halves for GEMM3)
//   [49152,50176)  s_g[256]
//   [50176,52224)  s_base[512]
//   [52224,52608)  s_rel[32][3]
// GEMM3 is K-split: write h2 cols [h*256,h*256+256) -> barrier -> 8 k-steps.
// GEMM2 col ownership col = n*64 + w*16 so each wave frees half its C2 regs
// at each write phase (VGPR peak ~130 < 168 @ 3 waves/SIMD).
// ---------------------------------------------------------------------------
__global__ __launch_bounds__(256, 3) void conv_kernel(
    const float* __restrict__ pos,
    const float* __restrict__ seed_pos,
    const int* __restrict__ nbr,
    const float* __restrict__ W1a, const float* __restrict__ b1a,
    const float* __restrict__ b1b,
    const float* __restrict__ W2a, const float* __restrict__ b2a,
    const float* __restrict__ b2b,
    const unsigned short* __restrict__ W1bt_h, const unsigned short* __restrict__ W1bt_l,
    const unsigned short* __restrict__ W2at_h, const unsigned short* __restrict__ W2at_l,
    const unsigned short* __restrict__ W2bt_h, const unsigned short* __restrict__ W2bt_l,
    float* __restrict__ out)
{
    __shared__ __align__(16) unsigned char smem[52608];
    unsigned char* sH1h = smem;                  // [32][256B]
    unsigned char* sH1l = smem + 8192;           // [32][256B]
    unsigned char* sA2h = smem + 16384;          // [32][512B]
    unsigned char* sA2l = smem + 32768;          // [32][512B]
    unsigned char* sA3h = smem;                  // [32][512B]  (aliases H1/A2h)
    unsigned char* sA3l = smem + 16384;          // [32][512B]
    float* s_g    = (float*)(smem + 49152);      // [256]
    float* s_base = (float*)(smem + 50176);      // [512]
    float* s_rel  = (float*)(smem + 52224);      // [32][3]

    const int blk = blockIdx.x;                  // seed 0..1023
    const int b   = blk >> 7;
    const int t   = threadIdx.x;
    const int w   = t >> 6;
    const int l   = t & 63;
    const int lg  = l >> 4;
    const int l15 = l & 15;

    // ---- stage 0: gather rel ----
    if (t < KK) {
        const int pi = nbr[blk * KK + t];
        const float* pp = pos + ((size_t)b * NN + pi) * 3;
        s_rel[t * 3 + 0] = pp[0] - seed_pos[blk * 3 + 0];
        s_rel[t * 3 + 1] = pp[1] - seed_pos[blk * 3 + 1];
        s_rel[t * 3 + 2] = pp[2] - seed_pos[blk * 3 + 2];
    }
    __syncthreads();

    // ---- stage 1: h1 = relu(rel@W1a + b1a) -> H1 hi/lo (swizzled) ----
    {
        const int j  = t & 127;
        const int rg = t >> 7;
        const float w0 = W1a[j], w1 = W1a[128 + j], w2 = W1a[256 + j], bb = b1a[j];
#pragma unroll
        for (int rr = 0; rr < 16; ++rr) {
            const int row = rg * 16 + rr;
            float v = fmaf(s_rel[row * 3 + 2], w2,
                      fmaf(s_rel[row * 3 + 1], w1,
                      fmaf(s_rel[row * 3 + 0], w0, bb)));
            v = fmaxf(v, 0.0f);
            const unsigned short hi = f2bf(v);
            const unsigned short lo = f2bf(v - bf2f(hi));
            const int byte = (j * 2) ^ ((row & 7) << 4);
            *(unsigned short*)(sH1h + row * 256 + byte) = hi;
            *(unsigned short*)(sH1l + row * 256 + byte) = lo;
        }
    }
    __syncthreads();

    // ---- GEMM1: f = h1 @ W1b (M=32,N=256,K=128); epi -> A2, s_g ----
    {
        f32x4 C1[2][4];
#pragma unroll
        for (int m = 0; m < 2; ++m)
#pragma unroll
            for (int i = 0; i < 4; ++i) C1[m][i] = (f32x4){0.f, 0.f, 0.f, 0.f};
#pragma unroll
        for (int ks = 0; ks < 4; ++ks) {
            s16x8 ah[2], al[2], bh[4], bl[4];
#pragma unroll
            for (int m = 0; m < 2; ++m) {
                const int row = m * 16 + l15;
                const int byte = (lg * 16 + ks * 64) ^ ((row & 7) << 4);
                ah[m] = *(const s16x8*)(sH1h + row * 256 + byte);
                al[m] = *(const s16x8*)(sH1l + row * 256 + byte);
            }
#pragma unroll
            for (int i = 0; i < 4; ++i) {
                const int ncol = w * 64 + i * 16 + l15;
                const size_t off = (size_t)ncol * 128 + lg * 8 + ks * 32;
                bh[i] = *(const s16x8*)(W1bt_h + off);
                bl[i] = *(const s16x8*)(W1bt_l + off);
            }
#pragma unroll
            for (int i = 0; i < 4; ++i)
#pragma unroll
                for (int m = 0; m < 2; ++m) C1[m][i] = mfma16(ah[m], bh[i], C1[m][i]);
#pragma unroll
            for (int i = 0; i < 4; ++i)
#pragma unroll
                for (int m = 0; m < 2; ++m) C1[m][i] = mfma16(ah[m], bl[i], C1[m][i]);
#pragma unroll
            for (int i = 0; i < 4; ++i)
#pragma unroll
                for (int m = 0; m < 2; ++m) C1[m][i] = mfma16(al[m], bh[i], C1[m][i]);
        }
#pragma unroll
        for (int i = 0; i < 4; ++i) {
            const int col = w * 64 + i * 16 + l15;
            const float bias = b1b[col];
            float pm = -INFINITY;
#pragma unroll
            for (int m = 0; m < 2; ++m)
#pragma unroll
                for (int r = 0; r < 4; ++r) {
                    const float v = C1[m][i][r] + bias;
                    pm = fmaxf(pm, v);
                    const int row = m * 16 + lg * 4 + r;
                    const unsigned short hi = f2bf(v);
                    const unsigned short lo = f2bf(v - bf2f(hi));
                    const int byte = (col * 2) ^ ((row & 7) << 4);
                    *(unsigned short*)(sA2h + row * 512 + byte) = hi;
                    *(unsigned short*)(sA2l + row * 512 + byte) = lo;
                }
            pm = fmaxf(pm, __shfl_xor(pm, 16));
            pm = fmaxf(pm, __shfl_xor(pm, 32));
            if (lg == 0) s_g[col] = pm;
        }
    }
    __syncthreads();

    // ---- base[c] = b2a[c] + g @ W2a[0:256] ----
    {
        float acc0 = b2a[t];
        float acc1 = b2a[256 + t];
#pragma unroll 4
        for (int j = 0; j < 256; j += 4) {
            const float g0 = s_g[j], g1 = s_g[j + 1], g2 = s_g[j + 2], g3 = s_g[j + 3];
            const float* wp = W2a + (size_t)j * 512 + t;
            acc0 = fmaf(g0, wp[0],    acc0);  acc1 = fmaf(g0, wp[256],  acc1);
            acc0 = fmaf(g1, wp[512],  acc0);  acc1 = fmaf(g1, wp[768],  acc1);
            acc0 = fmaf(g2, wp[1024], acc0);  acc1 = fmaf(g2, wp[1280], acc1);
            acc0 = fmaf(g3, wp[1536], acc0);  acc1 = fmaf(g3, wp[1792], acc1);
        }
        s_base[t] = acc0;
        s_base[256 + t] = acc1;
    }
    __syncthreads();

    // ---- GEMM2: C2 = f @ W2a[256:] (M=32,N=512,K=256); cols n*64+w*16 ----
    f32x4 C2[2][8];
#pragma unroll
    for (int m = 0; m < 2; ++m)
#pragma unroll
        for (int n = 0; n < 8; ++n) C2[m][n] = (f32x4){0.f, 0.f, 0.f, 0.f};
#pragma unroll 2
    for (int ks = 0; ks < 8; ++ks) {
        s16x8 ah[2], al[2];
#pragma unroll
        for (int m = 0; m < 2; ++m) {
            const int row = m * 16 + l15;
            const int byte = (lg * 16 + ks * 64) ^ ((row & 7) << 4);
            ah[m] = *(const s16x8*)(sA2h + row * 512 + byte);
            al[m] = *(const s16x8*)(sA2l + row * 512 + byte);
        }
#pragma unroll
        for (int c = 0; c < 2; ++c) {
            s16x8 bh[4], bl[4];
#pragma unroll
            for (int q = 0; q < 4; ++q) {
                const int n = c * 4 + q;
                const int ncol = n * 64 + w * 16 + l15;
                const size_t off = (size_t)ncol * 256 + lg * 8 + ks * 32;
                bh[q] = *(const s16x8*)(W2at_h + off);
                bl[q] = *(const s16x8*)(W2at_l + off);
            }
#pragma unroll
            for (int q = 0; q < 4; ++q)
#pragma unroll
                for (int m = 0; m < 2; ++m) C2[m][c * 4 + q] = mfma16(ah[m], bh[q], C2[m][c * 4 + q]);
#pragma unroll
            for (int q = 0; q < 4; ++q)
#pragma unroll
                for (int m = 0; m < 2; ++m) C2[m][c * 4 + q] = mfma16(ah[m], bl[q], C2[m][c * 4 + q]);
#pragma unroll
            for (int q = 0; q < 4; ++q)
#pragma unroll
                for (int m = 0; m < 2; ++m) C2[m][c * 4 + q] = mfma16(al[m], bh[q], C2[m][c * 4 + q]);
        }
    }
    __syncthreads();   // A2/H1 fully read; A3 region may be overwritten now

    // ---- GEMM3, K-split in two halves through one 32KB h2 staging buffer ----
    f32x4 C3[2][6];
#pragma unroll
    for (int m = 0; m < 2; ++m)
#pragma unroll
        for (int n = 0; n < 6; ++n) C3[m][n] = (f32x4){0.f, 0.f, 0.f, 0.f};

#pragma unroll
    for (int h = 0; h < 2; ++h) {
        // write phase: h2 cols [h*256, h*256+256) = relu(C2 + base), hi/lo split
#pragma unroll
        for (int q = 0; q < 4; ++q) {
            const int n = h * 4 + q;
            const int col = n * 64 + w * 16 + l15;
            const int colLocal = col - h * 256;
            const float bs = s_base[col];
#pragma unroll
            for (int m = 0; m < 2; ++m)
#pragma unroll
                for (int r = 0; r < 4; ++r) {
                    const float v = fmaxf(C2[m][n][r] + bs, 0.0f);
                    const int row = m * 16 + lg * 4 + r;
                    const unsigned short hi = f2bf(v);
                    const unsigned short lo = f2bf(v - bf2f(hi));
                    const int byte = (colLocal * 2) ^ ((row & 7) << 4);
                    *(unsigned short*)(sA3h + row * 512 + byte) = hi;
                    *(unsigned short*)(sA3l + row * 512 + byte) = lo;
                }
        }
        __syncthreads();

        // 8 k-steps over this half
        const int koff = h * 256;
#pragma unroll 2
        for (int ks = 0; ks < 8; ++ks) {
            s16x8 ah[2], al[2];
#pragma unroll
            for (int m = 0; m < 2; ++m) {
                const int row = m * 16 + l15;
                const int byte = (lg * 16 + ks * 64) ^ ((row & 7) << 4);
                ah[m] = *(const s16x8*)(sA3h + row * 512 + byte);
                al[m] = *(const s16x8*)(sA3l + row * 512 + byte);
            }
#pragma unroll
            for (int c = 0; c < 2; ++c) {
                s16x8 bh[3], bl[3];
#pragma unroll
                for (int q = 0; q < 3; ++q) {
                    const int n = c * 3 + q;
                    const int ncol = w * 96 + n * 16 + l15;
                    const size_t off = (size_t)ncol * 512 + koff + lg * 8 + ks * 32;
                    bh[q] = *(const s16x8*)(W2bt_h + off);
                    bl[q] = *(const s16x8*)(W2bt_l + off);
                }
#pragma unroll
                for (int q = 0; q < 3; ++q)
#pragma unroll
                    for (int m = 0; m < 2; ++m) C3[m][c * 3 + q] = mfma16(ah[m], bh[q], C3[m][c * 3 + q]);
#pragma unroll
                for (int q = 0; q < 3; ++q)
#pragma unroll
                    for (int m = 0; m < 2; ++m) C3[m][c * 3 + q] = mfma16(ah[m], bl[q], C3[m][c * 3 + q]);
#pragma unroll
                for (int q = 0; q < 3; ++q)
#pragma unroll
                    for (int m = 0; m < 2; ++m) C3[m][c * 3 + q] = mfma16(al[m], bh[q], C3[m][c * 3 + q]);
            }
        }
        if (h == 0) __syncthreads();   // buffer re-written next iteration
    }

    // ---- epilogue: out = colmax(e) + b2b ----
#pragma unroll
    for (int n = 0; n < 6; ++n) {
        const int col = w * 96 + n * 16 + l15;
        float pm = -INFINITY;
#pragma unroll
        for (int m = 0; m < 2; ++m)
#pragma unroll
            for (int r = 0; r < 4; ++r) pm = fmaxf(pm, C3[m][n][r]);
        pm = fmaxf(pm, __shfl_xor(pm, 16));
        pm = fmaxf(pm, __shfl_xor(pm, 32));
        if (lg == 0) out[(size_t)blk * EMB + col] = pm + b2b[col];
    }
}

// ---------------------------------------------------------------------------
extern "C" void kernel_launch(void* const* d_in, const int* in_sizes, int n_in,
                              void* d_out, int out_size, void* d_ws, size_t ws_size,
                              hipStream_t stream)
{
    const float* pos = (const float*)d_in[0];
    const float* W1a = (const float*)d_in[2];
    const float* b1a = (const float*)d_in[3];
    const float* W1b = (const float*)d_in[4];
    const float* b1b = (const float*)d_in[5];
    const float* W2a = (const float*)d_in[6];
    const float* b2a = (const float*)d_in[7];
    const float* W2b = (const float*)d_in[8];
    const float* b2b = (const float*)d_in[9];
    float* out = (float*)d_out;

    unsigned char* ws = (unsigned char*)d_ws;
    float* seed_pos = (float*)(ws + 0);                         // 12 KB
    int*   nbr      = (int*)(ws + 16384);                       // 128 KB
    unsigned short* W1bt_h = (unsigned short*)(ws + 147456);    // [256][128]
    unsigned short* W1bt_l = (unsigned short*)(ws + 212992);
    unsigned short* W2at_h = (unsigned short*)(ws + 278528);    // [512][256]
    unsigned short* W2at_l = (unsigned short*)(ws + 540672);
    unsigned short* W2bt_h = (unsigned short*)(ws + 802816);    // [384][512]
    unsigned short* W2bt_l = (unsigned short*)(ws + 1196032);

    prep_all<<<1408, 256, 0, stream>>>(W1b, W2a, W2b,
                                       W1bt_h, W1bt_l, W2at_h, W2at_l, W2bt_h, W2bt_l);
    fps_kernel<<<BB, 64, 0, stream>>>(pos, seed_pos);
    knn_kernel<<<BB * SS / 8, 512, 0, stream>>>(pos, seed_pos, nbr);
    conv_kernel<<<BB * SS, 256, 0, stream>>>(pos, seed_pos, nbr,
                                             W1a, b1a, b1b, W2a, b2a, b2b,
                                             W1bt_h, W1bt_l, W2at_h, W2at_l,
                                             W2bt_h, W2bt_l, out);
}

// Round 4
// 265.653 us; speedup vs baseline: 3.0518x; 1.4263x over previous
//
#include <hip/hip_runtime.h>
#include <math.h>

#define BB   8
#define NN   1024
#define SS   128
#define KK   32
#define EMB  384

// padded K strides (elements) for transposed split weights
#define KP1  136   // W1bt [256][136]
#define KP2  264   // W2at [512][264]
#define KP3  520   // W2bt [384][520]

typedef __attribute__((ext_vector_type(4))) float f32x4;
typedef __attribute__((ext_vector_type(8))) short s16x8;

__device__ __forceinline__ unsigned short f2bf(float x) {
    unsigned u = __float_as_uint(x);
    unsigned r = (u + 0x7FFFu + ((u >> 16) & 1u)) >> 16;   // RN-even
    return (unsigned short)r;
}
__device__ __forceinline__ float bf2f(unsigned short h) {
    return __uint_as_float(((unsigned)h) << 16);
}
__device__ __forceinline__ f32x4 mfma16(s16x8 a, s16x8 b, f32x4 c) {
    return __builtin_amdgcn_mfma_f32_16x16x32_bf16(a, b, c, 0, 0, 0);
}

// ---------------------------------------------------------------------------
// pre_kernel: blocks 0..7 = FPS (one wave per cloud, verified round 2/3);
// blocks 8..359 = tiled transpose + bf16 hi/lo split of the three weight
// matrices into padded [N][Kp] layouts (coalesced reads AND writes).
// ---------------------------------------------------------------------------
__global__ __launch_bounds__(256) void pre_kernel(
    const float* __restrict__ pos, float* __restrict__ seed_pos,
    const float* __restrict__ W1b, const float* __restrict__ W2a,
    const float* __restrict__ W2b,
    unsigned short* __restrict__ W1bt_h, unsigned short* __restrict__ W1bt_l,
    unsigned short* __restrict__ W2at_h, unsigned short* __restrict__ W2at_l,
    unsigned short* __restrict__ W2bt_h, unsigned short* __restrict__ W2bt_l)
{
    const int bid = blockIdx.x;
    if (bid < BB) {
        // ---------------- FPS ----------------
        if (threadIdx.x >= 64) return;
        const int b = bid;
        const int l = threadIdx.x;
        const float* p = pos + (size_t)b * NN * 3;

        float px[16], py[16], pz[16], mind[16];
#pragma unroll
        for (int r = 0; r < 16; ++r) {
            const int i = r * 64 + l;
            px[r] = p[i * 3 + 0];
            py[r] = p[i * 3 + 1];
            pz[r] = p[i * 3 + 2];
            mind[r] = INFINITY;
        }
        float sx = __shfl(px[0], 0), sy = __shfl(py[0], 0), sz = __shfl(pz[0], 0);
        for (int s = 0; s < SS; ++s) {
            if (l == 0) {
                seed_pos[((size_t)b * SS + s) * 3 + 0] = sx;
                seed_pos[((size_t)b * SS + s) * 3 + 1] = sy;
                seed_pos[((size_t)b * SS + s) * 3 + 2] = sz;
            }
            if (s == SS - 1) break;
            float best = -INFINITY;
            int bi = 0;
#pragma unroll
            for (int r = 0; r < 16; ++r) {
                const float dx = __fsub_rn(px[r], sx);
                const float dy = __fsub_rn(py[r], sy);
                const float dz = __fsub_rn(pz[r], sz);
                const float d = __fadd_rn(__fadd_rn(__fmul_rn(dx, dx), __fmul_rn(dy, dy)),
                                          __fmul_rn(dz, dz));
                mind[r] = fminf(mind[r], d);
                if (mind[r] > best) { best = mind[r]; bi = r * 64 + l; }
            }
#pragma unroll
            for (int off = 1; off < 64; off <<= 1) {
                const float ov = __shfl_xor(best, off);
                const int   oi = __shfl_xor(bi, off);
                if (ov > best || (ov == best && oi < bi)) { best = ov; bi = oi; }
            }
            const int wr = bi >> 6, wl = bi & 63;
            float cx = 0.f, cy = 0.f, cz = 0.f;
#pragma unroll
            for (int r = 0; r < 16; ++r) {
                if (r == wr) { cx = px[r]; cy = py[r]; cz = pz[r]; }
            }
            sx = __shfl(cx, wl); sy = __shfl(cy, wl); sz = __shfl(cz, wl);
        }
        return;
    }

    // ---------------- weight prep: 32x32 tile transpose + split ----------------
    __shared__ float tile[32][33];
    int tid = bid - BB;
    const float* src;
    unsigned short *dh, *dl;
    int N, Kp, koff, kt, nt;
    if (tid < 32) {
        src = W1b; dh = W1bt_h; dl = W1bt_l; N = 256; Kp = KP1; koff = 0;
        kt = tid >> 3; nt = tid & 7;
    } else if (tid < 160) {
        tid -= 32;
        src = W2a; dh = W2at_h; dl = W2at_l; N = 512; Kp = KP2; koff = 256;
        kt = tid >> 4; nt = tid & 15;
    } else {
        tid -= 160;
        src = W2b; dh = W2bt_h; dl = W2bt_l; N = 384; Kp = KP3; koff = 0;
        kt = tid / 12; nt = tid % 12;
    }
    const int k0 = kt * 32, n0 = nt * 32;
    const int tx = threadIdx.x & 31, ty = threadIdx.x >> 5;   // ty 0..7
#pragma unroll
    for (int i = 0; i < 4; ++i) {
        const int kl = ty + i * 8;
        tile[kl][tx] = src[(size_t)(k0 + kl + koff) * N + n0 + tx];
    }
    __syncthreads();
#pragma unroll
    for (int i = 0; i < 4; ++i) {
        const int nl = ty + i * 8;
        const float x = tile[tx][nl];
        const unsigned short hi = f2bf(x);
        const unsigned short lo = f2bf(x - bf2f(hi));
        const size_t o = (size_t)(n0 + nl) * Kp + k0 + tx;
        dh[o] = hi;
        dl[o] = lo;
    }
}

// ---------------------------------------------------------------------------
// kNN: wave-per-seed (verified round 3).
// ---------------------------------------------------------------------------
__global__ __launch_bounds__(512) void knn_kernel(
    const float* __restrict__ pos,
    const float* __restrict__ seed_pos,
    int* __restrict__ nbr)
{
    __shared__ float sx_[NN], sy_[NN], sz_[NN];
    const int blk = blockIdx.x;            // 0..127
    const int b   = blk >> 4;
    const int t   = threadIdx.x;
    const int w   = t >> 6;
    const int l   = t & 63;
    const float* p = pos + (size_t)b * NN * 3;

    for (int i = t; i < NN; i += 512) {
        sx_[i] = p[i * 3 + 0];
        sy_[i] = p[i * 3 + 1];
        sz_[i] = p[i * 3 + 2];
    }
    __syncthreads();

    const int gsid = b * SS + (blk & 15) * 8 + w;
    const float cx = seed_pos[gsid * 3 + 0];
    const float cy = seed_pos[gsid * 3 + 1];
    const float cz = seed_pos[gsid * 3 + 2];

    float d[16];
#pragma unroll
    for (int r = 0; r < 16; ++r) {
        const int i = r * 64 + l;
        const float dx = __fsub_rn(sx_[i], cx);
        const float dy = __fsub_rn(sy_[i], cy);
        const float dz = __fsub_rn(sz_[i], cz);
        d[r] = __fadd_rn(__fadd_rn(__fmul_rn(dx, dx), __fmul_rn(dy, dy)),
                         __fmul_rn(dz, dz));
    }

    for (int it = 0; it < KK; ++it) {
        float best = INFINITY;
        int bi = NN;
#pragma unroll
        for (int r = 0; r < 16; ++r) {
            if (d[r] < best) { best = d[r]; bi = r * 64 + l; }
        }
#pragma unroll
        for (int off = 1; off < 64; off <<= 1) {
            const float ov = __shfl_xor(best, off);
            const int   oi = __shfl_xor(bi, off);
            if (ov < best || (ov == best && oi < bi)) { best = ov; bi = oi; }
        }
        const int wr = bi >> 6, wl = bi & 63;
#pragma unroll
        for (int r = 0; r < 16; ++r) {
            if (r == wr && l == wl) d[r] = INFINITY;
        }
        if (l == 0) nbr[(size_t)gsid * KK + it] = bi;
    }
}

// ---------------------------------------------------------------------------
// PointConv, M=64 (2 seeds per block), 8 waves (512 threads), 1 block/CU.
// LDS map (105,216 B):
//   H1 hi [0,16384) lo [16384,32768)     rows [64][256B]
//   A2 hi [32768,65536) lo [65536,98304) rows [64][512B]
//   A3 hi [0,32768)  lo [32768,65536)    rows [64][512B]  (aliases H1+A2h, dead)
//   s_g    [2][256] f32 @98304
//   s_base [2][512] f32 @100352
//   s_rel  [64][3]  f32 @104448
// Per-GEMM wave partition (8 waves):
//   GEMM1 N=256: 2 tiles/wave  (col = w*32 + i*16)
//   GEMM2 N=512: 4 tiles/wave  (col = n*128 + w*16; n<2 -> half0, n>=2 -> half1)
//   GEMM3 N=384: 3 tiles/wave  (col = w*48 + n*16), K-split in 2 halves of 256
// ---------------------------------------------------------------------------
__global__ __launch_bounds__(512, 2) void conv_kernel(
    const float* __restrict__ pos,
    const float* __restrict__ seed_pos,
    const int* __restrict__ nbr,
    const float* __restrict__ W1a, const float* __restrict__ b1a,
    const float* __restrict__ b1b,
    const float* __restrict__ W2a, const float* __restrict__ b2a,
    const float* __restrict__ b2b,
    const unsigned short* __restrict__ W1bt_h, const unsigned short* __restrict__ W1bt_l,
    const unsigned short* __restrict__ W2at_h, const unsigned short* __restrict__ W2at_l,
    const unsigned short* __restrict__ W2bt_h, const unsigned short* __restrict__ W2bt_l,
    float* __restrict__ out)
{
    __shared__ __align__(16) unsigned char smem[105216];
    unsigned char* sH1h = smem;
    unsigned char* sH1l = smem + 16384;
    unsigned char* sA2h = smem + 32768;
    unsigned char* sA2l = smem + 65536;
    unsigned char* sA3h = smem;
    unsigned char* sA3l = smem + 32768;
    float* s_g    = (float*)(smem + 98304);    // [2][256]
    float* s_base = (float*)(smem + 100352);   // [2][512]
    float* s_rel  = (float*)(smem + 104448);   // [64][3]

    const int blk = blockIdx.x;                // 0..511 -> seeds blk*2, blk*2+1
    const int t   = threadIdx.x;
    const int w   = t >> 6;
    const int l   = t & 63;
    const int lg  = l >> 4;
    const int l15 = l & 15;

    // ---- stage 0: gather rel for 64 rows (2 seeds x 32 neighbors) ----
    if (t < 64) {
        const int sl   = t >> 5;
        const int gsid = blk * 2 + sl;
        const int b    = gsid >> 7;
        const int pi   = nbr[(size_t)gsid * KK + (t & 31)];
        const float* pp = pos + ((size_t)b * NN + pi) * 3;
        s_rel[t * 3 + 0] = pp[0] - seed_pos[gsid * 3 + 0];
        s_rel[t * 3 + 1] = pp[1] - seed_pos[gsid * 3 + 1];
        s_rel[t * 3 + 2] = pp[2] - seed_pos[gsid * 3 + 2];
    }
    __syncthreads();

    // ---- stage 1: h1[64][128] = relu(rel@W1a + b1a) -> H1 hi/lo swizzled ----
    {
        const int j  = t & 127;
        const int rg = t >> 7;                 // 0..3, 16 rows each
        const float w0 = W1a[j], w1 = W1a[128 + j], w2 = W1a[256 + j], bb = b1a[j];
#pragma unroll
        for (int rr = 0; rr < 16; ++rr) {
            const int row = rg * 16 + rr;
            float v = fmaf(s_rel[row * 3 + 2], w2,
                      fmaf(s_rel[row * 3 + 1], w1,
                      fmaf(s_rel[row * 3 + 0], w0, bb)));
            v = fmaxf(v, 0.0f);
            const unsigned short hi = f2bf(v);
            const unsigned short lo = f2bf(v - bf2f(hi));
            const int byte = (j * 2) ^ ((row & 7) << 4);
            *(unsigned short*)(sH1h + row * 256 + byte) = hi;
            *(unsigned short*)(sH1l + row * 256 + byte) = lo;
        }
    }
    __syncthreads();

    // ---- GEMM1: f = h1 @ W1b (M=64,N=256,K=128) ----
    {
        f32x4 C1[4][2];
#pragma unroll
        for (int m = 0; m < 4; ++m)
#pragma unroll
            for (int i = 0; i < 2; ++i) C1[m][i] = (f32x4){0.f, 0.f, 0.f, 0.f};
#pragma unroll
        for (int ks = 0; ks < 4; ++ks) {
            s16x8 ah[4], al[4], bh[2], bl[2];
#pragma unroll
            for (int m = 0; m < 4; ++m) {
                const int row = m * 16 + l15;
                const int byte = (lg * 16 + ks * 64) ^ ((row & 7) << 4);
                ah[m] = *(const s16x8*)(sH1h + row * 256 + byte);
                al[m] = *(const s16x8*)(sH1l + row * 256 + byte);
            }
#pragma unroll
            for (int i = 0; i < 2; ++i) {
                const int ncol = w * 32 + i * 16 + l15;
                const size_t off = (size_t)ncol * KP1 + lg * 8 + ks * 32;
                bh[i] = *(const s16x8*)(W1bt_h + off);
                bl[i] = *(const s16x8*)(W1bt_l + off);
            }
#pragma unroll
            for (int i = 0; i < 2; ++i)
#pragma unroll
                for (int m = 0; m < 4; ++m) C1[m][i] = mfma16(ah[m], bh[i], C1[m][i]);
#pragma unroll
            for (int i = 0; i < 2; ++i)
#pragma unroll
                for (int m = 0; m < 4; ++m) C1[m][i] = mfma16(ah[m], bl[i], C1[m][i]);
#pragma unroll
            for (int i = 0; i < 2; ++i)
#pragma unroll
                for (int m = 0; m < 4; ++m) C1[m][i] = mfma16(al[m], bh[i], C1[m][i]);
        }
        // epi: A2 = split(f), per-seed colmax -> s_g
#pragma unroll
        for (int i = 0; i < 2; ++i) {
            const int col = w * 32 + i * 16 + l15;
            const float bias = b1b[col];
            float pm0 = -INFINITY, pm1 = -INFINITY;
#pragma unroll
            for (int m = 0; m < 4; ++m)
#pragma unroll
                for (int r = 0; r < 4; ++r) {
                    const float v = C1[m][i][r] + bias;
                    if (m < 2) pm0 = fmaxf(pm0, v); else pm1 = fmaxf(pm1, v);
                    const int row = m * 16 + lg * 4 + r;
                    const unsigned short hi = f2bf(v);
                    const unsigned short lo = f2bf(v - bf2f(hi));
                    const int byte = (col * 2) ^ ((row & 7) << 4);
                    *(unsigned short*)(sA2h + row * 512 + byte) = hi;
                    *(unsigned short*)(sA2l + row * 512 + byte) = lo;
                }
            pm0 = fmaxf(pm0, __shfl_xor(pm0, 16));
            pm0 = fmaxf(pm0, __shfl_xor(pm0, 32));
            pm1 = fmaxf(pm1, __shfl_xor(pm1, 16));
            pm1 = fmaxf(pm1, __shfl_xor(pm1, 32));
            if (lg == 0) { s_g[col] = pm0; s_g[256 + col] = pm1; }
        }
    }
    __syncthreads();

    // ---- base[seed][c] = b2a[c] + g_seed @ W2a[0:256]; W2a stream shared ----
    {
        const int c = t;                       // 0..511
        float a0 = b2a[c], a1 = b2a[c];
#pragma unroll 4
        for (int jj = 0; jj < 256; ++jj) {
            const float w_ = W2a[(size_t)jj * 512 + c];
            a0 = fmaf(s_g[jj],       w_, a0);
            a1 = fmaf(s_g[256 + jj], w_, a1);
        }
        s_base[c] = a0;
        s_base[512 + c] = a1;
    }
    __syncthreads();

    // ---- GEMM2: C2 = f @ W2a[256:] (M=64,N=512,K=256) ----
    f32x4 C2[4][4];
#pragma unroll
    for (int m = 0; m < 4; ++m)
#pragma unroll
        for (int n = 0; n < 4; ++n) C2[m][n] = (f32x4){0.f, 0.f, 0.f, 0.f};
#pragma unroll 2
    for (int ks = 0; ks < 8; ++ks) {
        s16x8 ah[4], al[4];
#pragma unroll
        for (int m = 0; m < 4; ++m) {
            const int row = m * 16 + l15;
            const int byte = (lg * 16 + ks * 64) ^ ((row & 7) << 4);
            ah[m] = *(const s16x8*)(sA2h + row * 512 + byte);
            al[m] = *(const s16x8*)(sA2l + row * 512 + byte);
        }
#pragma unroll
        for (int n = 0; n < 4; ++n) {
            const int ncol = n * 128 + w * 16 + l15;
            const size_t off = (size_t)ncol * KP2 + lg * 8 + ks * 32;
            const s16x8 bh = *(const s16x8*)(W2at_h + off);
            const s16x8 bl = *(const s16x8*)(W2at_l + off);
#pragma unroll
            for (int m = 0; m < 4; ++m) C2[m][n] = mfma16(ah[m], bh, C2[m][n]);
#pragma unroll
            for (int m = 0; m < 4; ++m) C2[m][n] = mfma16(ah[m], bl, C2[m][n]);
#pragma unroll
            for (int m = 0; m < 4; ++m) C2[m][n] = mfma16(al[m], bh, C2[m][n]);
        }
    }
    __syncthreads();   // A2/H1 fully read; A3 region reusable

    // ---- GEMM3: e = h2 @ W2b, K-split through one 64KB staging buffer ----
    f32x4 C3[4][3];
#pragma unroll
    for (int m = 0; m < 4; ++m)
#pragma unroll
        for (int n = 0; n < 3; ++n) C3[m][n] = (f32x4){0.f, 0.f, 0.f, 0.f};

#pragma unroll
    for (int h = 0; h < 2; ++h) {
        // write phase: h2 cols [h*256, h*256+256) = relu(C2 + base)
#pragma unroll
        for (int q = 0; q < 2; ++q) {
            const int n = 2 * h + q;
            const int col  = n * 128 + w * 16 + l15;
            const int colL = q * 128 + w * 16 + l15;
            const float bs0 = s_base[col];
            const float bs1 = s_base[512 + col];
#pragma unroll
            for (int m = 0; m < 4; ++m)
#pragma unroll
                for (int r = 0; r < 4; ++r) {
                    const float v = fmaxf(C2[m][n][r] + (m < 2 ? bs0 : bs1), 0.0f);
                    const int row = m * 16 + lg * 4 + r;
                    const unsigned short hi = f2bf(v);
                    const unsigned short lo = f2bf(v - bf2f(hi));
                    const int byte = (colL * 2) ^ ((row & 7) << 4);
                    *(unsigned short*)(sA3h + row * 512 + byte) = hi;
                    *(unsigned short*)(sA3l + row * 512 + byte) = lo;
                }
        }
        __syncthreads();

        const int koff = h * 256;
#pragma unroll 2
        for (int ks = 0; ks < 8; ++ks) {
            s16x8 ah[4], al[4];
#pragma unroll
            for (int m = 0; m < 4; ++m) {
                const int row = m * 16 + l15;
                const int byte = (lg * 16 + ks * 64) ^ ((row & 7) << 4);
                ah[m] = *(const s16x8*)(sA3h + row * 512 + byte);
                al[m] = *(const s16x8*)(sA3l + row * 512 + byte);
            }
#pragma unroll
            for (int n = 0; n < 3; ++n) {
                const int ncol = w * 48 + n * 16 + l15;
                const size_t off = (size_t)ncol * KP3 + koff + lg * 8 + ks * 32;
                const s16x8 bh = *(const s16x8*)(W2bt_h + off);
                const s16x8 bl = *(const s16x8*)(W2bt_l + off);
#pragma unroll
                for (int m = 0; m < 4; ++m) C3[m][n] = mfma16(ah[m], bh, C3[m][n]);
#pragma unroll
                for (int m = 0; m < 4; ++m) C3[m][n] = mfma16(ah[m], bl, C3[m][n]);
#pragma unroll
                for (int m = 0; m < 4; ++m) C3[m][n] = mfma16(al[m], bh, C3[m][n]);
            }
        }
        if (h == 0) __syncthreads();           // staging buffer rewritten next h
    }

    // ---- epilogue: out[seed] = colmax(e_seed) + b2b ----
#pragma unroll
    for (int n = 0; n < 3; ++n) {
        const int col = w * 48 + n * 16 + l15;
        float pm0 = -INFINITY, pm1 = -INFINITY;
#pragma unroll
        for (int m = 0; m < 4; ++m)
#pragma unroll
            for (int r = 0; r < 4; ++r) {
                if (m < 2) pm0 = fmaxf(pm0, C3[m][n][r]);
                else       pm1 = fmaxf(pm1, C3[m][n][r]);
            }
        pm0 = fmaxf(pm0, __shfl_xor(pm0, 16));
        pm0 = fmaxf(pm0, __shfl_xor(pm0, 32));
        pm1 = fmaxf(pm1, __shfl_xor(pm1, 16));
        pm1 = fmaxf(pm1, __shfl_xor(pm1, 32));
        if (lg == 0) {
            out[(size_t)(blk * 2 + 0) * EMB + col] = pm0 + b2b[col];
            out[(size_t)(blk * 2 + 1) * EMB + col] = pm1 + b2b[col];
        }
    }
}

// ---------------------------------------------------------------------------
extern "C" void kernel_launch(void* const* d_in, const int* in_sizes, int n_in,
                              void* d_out, int out_size, void* d_ws, size_t ws_size,
                              hipStream_t stream)
{
    const float* pos = (const float*)d_in[0];
    const float* W1a = (const float*)d_in[2];
    const float* b1a = (const float*)d_in[3];
    const float* W1b = (const float*)d_in[4];
    const float* b1b = (const float*)d_in[5];
    const float* W2a = (const float*)d_in[6];
    const float* b2a = (const float*)d_in[7];
    const float* W2b = (const float*)d_in[8];
    const float* b2b = (const float*)d_in[9];
    float* out = (float*)d_out;

    // workspace layout (1,626,112 B)
    unsigned char* ws = (unsigned char*)d_ws;
    float* seed_pos = (float*)(ws + 0);                         // 12 KB
    int*   nbr      = (int*)(ws + 16384);                       // 128 KB
    unsigned short* W1bt_h = (unsigned short*)(ws + 147456);    // [256][136] 69632 B
    unsigned short* W1bt_l = (unsigned short*)(ws + 217088);    // 69632 B
    unsigned short* W2at_h = (unsigned short*)(ws + 286720);    // [512][264] 270336 B
    unsigned short* W2at_l = (unsigned short*)(ws + 557056);    // 270336 B
    unsigned short* W2bt_h = (unsigned short*)(ws + 827392);    // [384][520] 399360 B
    unsigned short* W2bt_l = (unsigned short*)(ws + 1226752);   // 399360 B

    pre_kernel<<<BB + 352, 256, 0, stream>>>(pos, seed_pos, W1b, W2a, W2b,
                                             W1bt_h, W1bt_l, W2at_h, W2at_l,
                                             W2bt_h, W2bt_l);
    knn_kernel<<<BB * SS / 8, 512, 0, stream>>>(pos, seed_pos, nbr);
    conv_kernel<<<BB * SS / 2, 512, 0, stream>>>(pos, seed_pos, nbr,
                                                 W1a, b1a, b1b, W2a, b2a, b2b,
                                                 W1bt_h, W1bt_l, W2at_h, W2at_l,
                                                 W2bt_h, W2bt_l, out);
}